// Round 11
// baseline (304.243 us; speedup 1.0000x reference)
//
#include <hip/hip_runtime.h>
#include <hip/hip_bf16.h>
#include <stdint.h>

#define S_LEN 2048
#define H_DIM 2048
#define NHEADS 16
#define KVHEADS 4
#define HEAD_DIM 128
#define KV_DIM 512       // KVHEADS * HEAD_DIM
#define NTOK 4096        // B * S
#define NQKV 3072        // H_DIM + 2*KV_DIM

typedef __bf16 bf16_t;
typedef __bf16 bf16x8 __attribute__((ext_vector_type(8)));
typedef __bf16 bf16x4 __attribute__((ext_vector_type(4)));
typedef float f32x4 __attribute__((ext_vector_type(4)));

__device__ __forceinline__ f32x4 mfma16x16x32(bf16x8 a, bf16x8 b, f32x4 c) {
    return __builtin_amdgcn_mfma_f32_16x16x32_bf16(a, b, c, 0, 0, 0);
}

// async global->LDS, 16B per lane. LDS dest = wave-uniform base + lane*16;
// global address may be fully per-lane (scatter side is global).
__device__ __forceinline__ void gload_lds16(const bf16_t* g, bf16_t* l) {
    __builtin_amdgcn_global_load_lds(
        (__attribute__((address_space(1))) uint32_t*)(uintptr_t)g,
        (__attribute__((address_space(3))) uint32_t*)l, 16, 0, 0);
}

// Fused fp32->bf16 convert of all 5 tensors in one launch (8 elems/thread).
// Wk rows ONLY are PERMUTED on the fly (round-5 bijection, verified): phys
// row head*128 + 64s + 16a + c takes logical row head*128 + 64(a&1) + 32s +
// 16(a>>1) + c. This places each RoPE pair (d, d+64) into the same
// gemm_qkv K-epilogue thread (ni=2P lo, ni=2P+1 hi); the epilogue rotates
// on the fp32 accumulator and writes K back at NATURAL dim positions, so
// Q/V/attn see no permutation anywhere.
#define N_X  (NTOK * H_DIM)     // 8388608
#define N_WQ (H_DIM * H_DIM)    // 4194304
#define N_WK (KV_DIM * H_DIM)   // 1048576
__global__ __launch_bounds__(256) void cvt_all(const float* __restrict__ X,
                                               const float* __restrict__ Wq,
                                               const float* __restrict__ Wk,
                                               const float* __restrict__ Wv,
                                               const float* __restrict__ Wo,
                                               bf16_t* __restrict__ Xb,
                                               bf16_t* __restrict__ Wqb,
                                               bf16_t* __restrict__ Wkb,
                                               bf16_t* __restrict__ Wvb,
                                               bf16_t* __restrict__ Wob) {
    long i = (long)(blockIdx.x * 256 + threadIdx.x) * 8;
    const float* src;
    bf16_t* dst;
    bool perm = false;
    if (i < N_X)                       { src = X;  dst = Xb; }
    else if ((i -= N_X) < N_WQ)        { src = Wq; dst = Wqb; }
    else if ((i -= N_WQ) < N_WK)       { src = Wk; dst = Wkb; perm = true; }
    else if ((i -= N_WK) < N_WK)       { src = Wv; dst = Wvb; }
    else      { i -= N_WK;               src = Wo; dst = Wob; }
    long isrc = i;
    if (perm) {
        const long jrow = i >> 11;          // dst row (2048 elems/row)
        const int  o    = (int)(i & 2047);
        const int  a    = (int)(jrow >> 4) & 3;
        const int  sh   = (int)(jrow >> 6) & 1;
        const long srow = (jrow & ~127L) | ((long)(a & 1) << 6) |
                          ((long)sh << 5) | ((long)(a >> 1) << 4) | (jrow & 15);
        isrc = srow * 2048 + o;
    }
    const float4 va = *(const float4*)(src + isrc);
    const float4 vb = *(const float4*)(src + isrc + 4);
    bf16x8 o;
    o[0] = (bf16_t)va.x; o[1] = (bf16_t)va.y; o[2] = (bf16_t)va.z; o[3] = (bf16_t)va.w;
    o[4] = (bf16_t)vb.x; o[5] = (bf16_t)vb.y; o[6] = (bf16_t)vb.z; o[7] = (bf16_t)vb.w;
    *(bf16x8*)(dst + i) = o;
}

// ---- GEMM main loop, BK=32 variant (m97 structure) ----
// Used by gemm_qkv (768 blocks, ~3/CU): at this concurrency the barrier
// drains are hidden by inter-block wave overlap (r7-r10 A/B: BK=32
// two-barrier 69us beats BK=64 76.5us and dbuf 80.4us on this grid).
#define GEMM_BODY32(A_, W_, K_)                                                \
    __shared__ alignas(16) bf16_t As[128 * 32];                                \
    __shared__ alignas(16) bf16_t Bs[128 * 32];                                \
    const int tid  = threadIdx.x;                                              \
    const int wave = tid >> 6;                                                 \
    const int lane = tid & 63;                                                 \
    const int col  = lane & 15;                                                \
    const int quad = lane >> 4;                                                \
    const int m0 = blockIdx.y * 128;                                           \
    const int n0 = blockIdx.x * 128;                                           \
    const int wm = (wave >> 1) * 64;                                           \
    const int wn = (wave & 1) * 64;                                            \
    const int r0 = tid >> 2;                                                   \
    const int kk = (tid & 3) * 8;                                              \
    const bf16_t* a0 = (A_) + (size_t)(m0 + r0) * (K_) + kk;                   \
    const bf16_t* a1 = a0 + (size_t)64 * (K_);                                 \
    const bf16_t* b0 = (W_) + (size_t)(n0 + r0) * (K_) + kk;                   \
    const bf16_t* b1 = b0 + (size_t)64 * (K_);                                 \
    bf16_t* lA0 = As + tid * 8;                                                \
    bf16_t* lA1 = As + 2048 + tid * 8;                                         \
    bf16_t* lB0 = Bs + tid * 8;                                                \
    bf16_t* lB1 = Bs + 2048 + tid * 8;                                         \
    f32x4 acc[4][4];                                                           \
    _Pragma("unroll") for (int mi = 0; mi < 4; ++mi)                           \
        _Pragma("unroll") for (int ni = 0; ni < 4; ++ni)                       \
            acc[mi][ni] = (f32x4){0.f, 0.f, 0.f, 0.f};                         \
    for (int k0 = 0; k0 < (K_); k0 += 32) {                                    \
        __syncthreads();                                                       \
        gload_lds16(a0 + k0, lA0);                                             \
        gload_lds16(a1 + k0, lA1);                                             \
        gload_lds16(b0 + k0, lB0);                                             \
        gload_lds16(b1 + k0, lB1);                                             \
        __syncthreads();                                                       \
        bf16x8 av[4], bv[4];                                                   \
        _Pragma("unroll") for (int i = 0; i < 4; ++i) {                        \
            av[i] = *(const bf16x8*)(As + (wm + i * 16 + col) * 32 + quad * 8);\
            bv[i] = *(const bf16x8*)(Bs + (wn + i * 16 + col) * 32 + quad * 8);\
        }                                                                      \
        _Pragma("unroll") for (int mi = 0; mi < 4; ++mi)                       \
            _Pragma("unroll") for (int ni = 0; ni < 4; ++ni)                   \
                acc[mi][ni] = mfma16x16x32(av[mi], bv[ni], acc[mi][ni]);       \
    }

// ---- GEMM main loop, BK=64 variant with XOR-swizzled staging ----
// Used by gemm_out (128 blocks, ~0.5/CU): no neighbor waves to hide the
// per-step vmcnt drain, so halving the barrier count pays (round-7/8 A/B:
// ~ -15 us on this grid). Reads are conflict-free via both-sides swizzle.
#define GEMM_BODY64(A_, W_, K_)                                                \
    __shared__ alignas(16) bf16_t As[128 * 64];                                \
    __shared__ alignas(16) bf16_t Bs[128 * 64];                                \
    const int tid  = threadIdx.x;                                              \
    const int wave = tid >> 6;                                                 \
    const int lane = tid & 63;                                                 \
    const int col  = lane & 15;                                                \
    const int quad = lane >> 4;                                                \
    const int m0 = blockIdx.y * 128;                                           \
    const int n0 = blockIdx.x * 128;                                           \
    const int wm = (wave >> 1) * 64;                                           \
    const int wn = (wave & 1) * 64;                                            \
    const int r0 = tid >> 3;             /* staging row in 32-row chunk */     \
    const int kk = ((tid & 7) ^ (r0 & 7)) * 8;  /* pre-swizzled k-chunk */     \
    const bf16_t* ab = (A_) + (size_t)(m0 + r0) * (K_) + kk;                   \
    const bf16_t* bb = (W_) + (size_t)(n0 + r0) * (K_) + kk;                   \
    bf16_t* lA = As + tid * 8;                                                 \
    bf16_t* lB = Bs + tid * 8;                                                 \
    const int swz = col & 7;                                                   \
    f32x4 acc[4][4];                                                           \
    _Pragma("unroll") for (int mi = 0; mi < 4; ++mi)                           \
        _Pragma("unroll") for (int ni = 0; ni < 4; ++ni)                       \
            acc[mi][ni] = (f32x4){0.f, 0.f, 0.f, 0.f};                         \
    for (int k0 = 0; k0 < (K_); k0 += 64) {                                    \
        __syncthreads();                                                       \
        _Pragma("unroll") for (int c = 0; c < 4; ++c) {                        \
            gload_lds16(ab + k0 + (size_t)(c * 32) * (K_), lA + c * 2048);     \
            gload_lds16(bb + k0 + (size_t)(c * 32) * (K_), lB + c * 2048);     \
        }                                                                      \
        __syncthreads();                                                       \
        _Pragma("unroll") for (int h = 0; h < 2; ++h) {                        \
            bf16x8 av[4], bv[4];                                               \
            _Pragma("unroll") for (int i = 0; i < 4; ++i) {                    \
                av[i] = *(const bf16x8*)(As + (wm + i * 16 + col) * 64 +       \
                                         (((h * 4 + quad) ^ swz) << 3));       \
                bv[i] = *(const bf16x8*)(Bs + (wn + i * 16 + col) * 64 +       \
                                         (((h * 4 + quad) ^ swz) << 3));       \
            }                                                                  \
            _Pragma("unroll") for (int mi = 0; mi < 4; ++mi)                   \
                _Pragma("unroll") for (int ni = 0; ni < 4; ++ni)               \
                    acc[mi][ni] = mfma16x16x32(av[mi], bv[ni], acc[mi][ni]);   \
        }                                                                      \
    }

#define QSCALE_LOG2E 0.12753102813264324f  // (1/sqrt(128)) * log2(e)

// Fused QKV projection: C row-major views into qbuf [M][2048] (n<2048),
// kbuf [M][512] (2048<=n<2560, with FUSED RoPE), and V^T layout
// [b][kvh*128+d][s] (n>=2560). The K branch holds RoPE pairs in-thread
// (Wk rows were permuted in cvt_all): rotate on the fp32 accumulator and
// store to NATURAL dim positions dlo = 32s + 16P + col and dlo+64. Only
// 4/24 block columns take this heavier path; its cos/sin latency hides
// under the q/v-branch neighbors.
__global__ __launch_bounds__(256) void gemm_qkv(const bf16_t* __restrict__ A,
                                                const bf16_t* __restrict__ W,
                                                const float* __restrict__ cosb,
                                                const float* __restrict__ sinb,
                                                bf16_t* __restrict__ qbuf,
                                                bf16_t* __restrict__ kbuf,
                                                bf16_t* __restrict__ vtbuf) {
    GEMM_BODY32(A, W, H_DIM)
    const int ng = n0 + wn;   // 64-aligned; q/k/v boundaries are 64-aligned
    if (ng < H_DIM) {
#pragma unroll
        for (int mi = 0; mi < 4; ++mi)
#pragma unroll
            for (int ni = 0; ni < 4; ++ni)
#pragma unroll
                for (int r = 0; r < 4; ++r)
                    qbuf[(size_t)(m0 + wm + mi * 16 + quad * 4 + r) * H_DIM +
                         ng + ni * 16 + col] = (bf16_t)acc[mi][ni][r];
    } else if (ng < H_DIM + KV_DIM) {
        const int nrel = ng - H_DIM;
        const int hb   = nrel & ~127;        // head base within kbuf row
        const int s    = (nrel >> 6) & 1;
#pragma unroll
        for (int mi = 0; mi < 4; ++mi) {
#pragma unroll
            for (int r = 0; r < 4; ++r) {
                const int m   = m0 + wm + mi * 16 + quad * 4 + r;
                const int tok = m & (S_LEN - 1);
                const float* cb = cosb + tok * HEAD_DIM;
                const float* sb = sinb + tok * HEAD_DIM;
#pragma unroll
                for (int P = 0; P < 2; ++P) {
                    const int dlo = s * 32 + P * 16 + col;
                    const float lo = acc[mi][2 * P][r];
                    const float hi = acc[mi][2 * P + 1][r];
                    kbuf[(size_t)m * KV_DIM + hb + dlo] =
                        (bf16_t)(lo * cb[dlo] - hi * sb[dlo]);
                    kbuf[(size_t)m * KV_DIM + hb + dlo + 64] =
                        (bf16_t)(hi * cb[dlo + 64] + lo * sb[dlo + 64]);
                }
            }
        }
    } else {
#pragma unroll
        for (int mi = 0; mi < 4; ++mi) {
            const int m = m0 + wm + mi * 16 + quad * 4;
#pragma unroll
            for (int ni = 0; ni < 4; ++ni) {
                const int nv = ng - (H_DIM + KV_DIM) + ni * 16 + col;
                const size_t off =
                    ((size_t)(m >> 11) * KV_DIM + nv) * S_LEN + (m & (S_LEN - 1));
                bf16x4 o;
#pragma unroll
                for (int r = 0; r < 4; ++r) o[r] = (bf16_t)acc[mi][ni][r];
                *(bf16x4*)(vtbuf + off) = o;
            }
        }
    }
}

// O projection: fp32 output.
__global__ __launch_bounds__(256) void gemm_out(const bf16_t* __restrict__ A,
                                                const bf16_t* __restrict__ W,
                                                float* __restrict__ C) {
    GEMM_BODY64(A, W, H_DIM)
#pragma unroll
    for (int mi = 0; mi < 4; ++mi)
#pragma unroll
        for (int ni = 0; ni < 4; ++ni)
#pragma unroll
            for (int r = 0; r < 4; ++r)
                C[(size_t)(m0 + wm + mi * 16 + quad * 4 + r) * H_DIM +
                  n0 + wn + ni * 16 + col] = (float)acc[mi][ni][r];
}

#define NEG_BIG (-1e30f)
#define TJ 64          // kv tile width
#define DEFER_THR 8.0f // defer-max threshold, log2 units (P bounded by 2^8)

// Flash attention, causal, transposed-score form.
// 8-wave (512-thread) blocks; waves 0-3 own q-tile 2i, waves 4-7 own 2i+1;
// shared K/V staging stream; complementary CU pairing (i = b? 63-jp : jp).
// Q-RoPE is FUSED into the prologue: qf[t][u] holds dim d = t*32+quad*8+u,
// its RoPE partner d+64 is qf[t+2][u] -- same lane, so the rotation (+ the
// scale*log2e fold) is 64 FMAs + 16 L2-hit float4 loads, once per block.
// Q in memory is now the RAW projection (rope kernel deleted).
// PV is K=32 MFMA with P^T staged through wave-private LDS scratch Ps;
// one __syncthreads per kv-step; PV operand order mfma(vf, aP) gives O^T
// (O[q=col][d]) -> broadcast-free alpha/l rescale and aligned bf16x4 stores.
__global__ __launch_bounds__(512, 4) void attn_fwd(bf16_t* __restrict__ Q,
                                                   const bf16_t* __restrict__ Kb,
                                                   const bf16_t* __restrict__ Vt,
                                                   const float* __restrict__ cosb,
                                                   const float* __restrict__ sinb) {
    const int id   = blockIdx.x;       // 0..511
    const int jp   = id & 63;
    const int kvh  = (id >> 6) & 3;
    const int b    = id >> 8;
    const int i    = b ? (63 - jp) : jp;   // complementary pairing per CU
    const int tid  = threadIdx.x;
    const int wave = tid >> 6;
    const int lane = tid & 63;
    const int col  = lane & 15;
    const int quad = lane >> 4;
    const int grp  = wave >> 2;        // 0: tile 2i, 1: tile 2i+1
    const int h    = kvh * 4 + (wave & 3);
    const int q0   = (2 * i + grp) * 16;
    const int nsteps = (i >> 1) + 1;
    const int swz  = col & 7;          // read-side swizzle key

    __shared__ alignas(16) bf16_t Ks[2][TJ * HEAD_DIM];    // 16 KB each
    __shared__ alignas(16) bf16_t Vs[2][HEAD_DIM * TJ];    // 16 KB each
    __shared__ alignas(16) bf16_t Ps[8 * 1024];            // 16 KB, wave-priv

    const bf16_t* kbase = Kb + (size_t)(b * S_LEN) * KV_DIM + kvh * HEAD_DIM;
    const bf16_t* vtb   = Vt + (size_t)(b * KVHEADS + kvh) * HEAD_DIM * S_LEN;

    // per-lane global element offsets for the 2 K + 2 V staging DMAs
    int kgoff[2], vgoff[2];
#pragma unroll
    for (int im = 0; im < 2; ++im) {
        const int s = im * 512 + tid;
        const int jr = s >> 4, c = (s & 15) ^ (jr & 7);
        kgoff[im] = jr * KV_DIM + c * 8;
        const int d = s >> 3, cj = (s & 7) ^ (d & 7);
        vgoff[im] = d * S_LEN + cj * 8;
    }
    auto stage = [&](int buf, int j0) {
        const bf16_t* kb = kbase + (size_t)j0 * KV_DIM;
        const bf16_t* vb = vtb + j0;
#pragma unroll
        for (int im = 0; im < 2; ++im) {
            gload_lds16(kb + kgoff[im], &Ks[buf][(im * 512 + wave * 64) * 8]);
            gload_lds16(vb + vgoff[im], &Vs[buf][(im * 512 + wave * 64) * 8]);
        }
    };

    // hoisted fragment LDS byte addrs; tile index goes into imm offsets:
    // K frag (t,jc): kaddr[t] + jc*4096;  V frag (half,dt): vb0/1 + dt*2048
    int kaddr[4];
#pragma unroll
    for (int t = 0; t < 4; ++t)
        kaddr[t] = col * 256 + (((4 * t + quad) ^ swz) << 4);
    const int vb0 = col * 128 + ((quad ^ swz) << 4);
    const int vb1 = col * 128 + (((quad + 4) ^ swz) << 4);
    // P^T scratch offsets (wave-private 2 KB slice of Ps)
    int pwoff[4];
#pragma unroll
    for (int jc = 0; jc < 4; ++jc)
        pwoff[jc] = wave * 2048 +
                    ((col * 128 + jc * 32 + quad * 8) ^ (swz << 4));
    const int ap0 = wave * 2048 + ((col * 128 + quad * 16) ^ (swz << 4));
    const int ap1 = wave * 2048 + ((col * 128 + 64 + quad * 16) ^ (swz << 4));

#define ATTN_STEP(JT, BUF)                                                     \
    {                                                                          \
        const int jt_ = (JT);                                                  \
        const bool last_ = (jt_ == nsteps - 1);                                \
        __syncthreads();  /* vmcnt(0) drain: buf BUF staged; prev reads done */\
        if (!last_) stage((BUF) ^ 1, (jt_ + 1) * TJ);                          \
        const char* ksb = (const char*)Ks[(BUF)];                              \
        const char* vsb = (const char*)Vs[(BUF)];                              \
        char* pwb = (char*)Ps;          /* wave-private P^T scratch */         \
        f32x4 sc[4];                                                           \
        _Pragma("unroll") for (int jc = 0; jc < 4; ++jc)                       \
            sc[jc] = (f32x4){0.f, 0.f, 0.f, 0.f};                              \
        __builtin_amdgcn_s_setprio(1);                                         \
        _Pragma("unroll") for (int t = 0; t < 4; ++t)                          \
            _Pragma("unroll") for (int jc = 0; jc < 4; ++jc)                   \
                sc[jc] = mfma16x16x32(                                         \
                    *(const bf16x8*)(ksb + kaddr[t] + jc * 4096), qf[t],       \
                    sc[jc]);                                                   \
        __builtin_amdgcn_s_setprio(0);                                         \
        if (last_) {                                                           \
            const int j0_ = jt_ * TJ;                                          \
            const int q_ = q0 + col;                                           \
            _Pragma("unroll") for (int jc = 0; jc < 4; ++jc)                   \
                _Pragma("unroll") for (int r = 0; r < 4; ++r) {                \
                    const int j = j0_ + jc * 16 + quad * 4 + r;                \
                    if (j > q_) sc[jc][r] = NEG_BIG;                           \
                }                                                              \
        }                                                                      \
        float mx = sc[0][0];                                                   \
        _Pragma("unroll") for (int jc = 0; jc < 4; ++jc)                       \
            _Pragma("unroll") for (int r = 0; r < 4; ++r)                      \
                mx = fmaxf(mx, sc[jc][r]);                                     \
        /* per-lane partial max is a lower bound of the column max: if no  */  \
        /* lane exceeds m_i+THR, no column max does -> skip reduce+rescale */  \
        if (!__all(mx <= m_i + DEFER_THR)) {                                   \
            mx = fmaxf(mx, __shfl_xor(mx, 16));                                \
            mx = fmaxf(mx, __shfl_xor(mx, 32));                                \
            const float mn = fmaxf(m_i, mx);                                   \
            const float alpha = __builtin_amdgcn_exp2f(m_i - mn);              \
            m_i = mn;                                                          \
            l_i *= alpha;                                                      \
            _Pragma("unroll") for (int dt = 0; dt < 8; ++dt)                   \
                Oacc[dt] *= alpha;  /* O rows are q=col: no broadcast */       \
        }                                                                      \
        float sum = 0.f;                                                       \
        bf16x4 pb[4];                                                          \
        _Pragma("unroll") for (int jc = 0; jc < 4; ++jc)                       \
            _Pragma("unroll") for (int r = 0; r < 4; ++r) {                    \
                const float pe = __builtin_amdgcn_exp2f(sc[jc][r] - m_i);      \
                sum += pe;                                                     \
                pb[jc][r] = (bf16_t)pe;                                        \
            }                                                                  \
        _Pragma("unroll") for (int jc = 0; jc < 4; ++jc)                       \
            *(bf16x4*)(pwb + pwoff[jc]) = pb[jc];                              \
        sum += __shfl_xor(sum, 16);                                            \
        sum += __shfl_xor(sum, 32);                                            \
        l_i += sum;                                                            \
        asm volatile("s_waitcnt lgkmcnt(0)" ::: "memory");  /* P visible */    \
        const bf16x8 aP0 = *(const bf16x8*)(pwb + ap0);                        \
        const bf16x8 aP1 = *(const bf16x8*)(pwb + ap1);                        \
        __builtin_amdgcn_s_setprio(1);                                         \
        _Pragma("unroll") for (int dt = 0; dt < 8; ++dt) {                     \
            const bf16x8 vf0 = *(const bf16x8*)(vsb + vb0 + dt * 2048);        \
            const bf16x8 vf1 = *(const bf16x8*)(vsb + vb1 + dt * 2048);        \
            Oacc[dt] = mfma16x16x32(vf1, aP1,                                  \
                       mfma16x16x32(vf0, aP0, Oacc[dt]));                      \
        }                                                                      \
        __builtin_amdgcn_s_setprio(0);                                         \
    }

    stage(0, 0);

    // Q load + in-register RoPE (+ scale*log2e fold). qf[t][u] holds dim
    // d = t*32 + quad*8 + u; partner d+64 lives in qf[t+2][u].
    bf16x8 qf[4];
    {
        const bf16_t* qp = Q + (size_t)(b * S_LEN + q0 + col) * H_DIM +
                           h * HEAD_DIM + quad * 8;
#pragma unroll
        for (int t = 0; t < 4; ++t) qf[t] = *(const bf16x8*)(qp + t * 32);
        const float* cq = cosb + (size_t)(q0 + col) * HEAD_DIM + quad * 8;
        const float* sq = sinb + (size_t)(q0 + col) * HEAD_DIM + quad * 8;
#pragma unroll
        for (int t = 0; t < 2; ++t) {
            float c0[8], s0[8], c1[8], s1[8];
            *(float4*)&c0[0] = *(const float4*)(cq + t * 32);
            *(float4*)&c0[4] = *(const float4*)(cq + t * 32 + 4);
            *(float4*)&s0[0] = *(const float4*)(sq + t * 32);
            *(float4*)&s0[4] = *(const float4*)(sq + t * 32 + 4);
            *(float4*)&c1[0] = *(const float4*)(cq + t * 32 + 64);
            *(float4*)&c1[4] = *(const float4*)(cq + t * 32 + 68);
            *(float4*)&s1[0] = *(const float4*)(sq + t * 32 + 64);
            *(float4*)&s1[4] = *(const float4*)(sq + t * 32 + 68);
#pragma unroll
            for (int u = 0; u < 8; ++u) {
                const float lo = (float)qf[t][u];
                const float hi = (float)qf[t + 2][u];
                qf[t][u] =
                    (bf16_t)((lo * c0[u] - hi * s0[u]) * QSCALE_LOG2E);
                qf[t + 2][u] =
                    (bf16_t)((hi * c1[u] + lo * s1[u]) * QSCALE_LOG2E);
            }
        }
    }
    f32x4 Oacc[8];
#pragma unroll
    for (int dt = 0; dt < 8; ++dt) Oacc[dt] = (f32x4){0.f, 0.f, 0.f, 0.f};
    float m_i = NEG_BIG, l_i = 0.f;

    int jt = 0;
    while (true) {
        ATTN_STEP(jt, 0)
        if (++jt == nsteps) break;
        ATTN_STEP(jt, 1)
        if (++jt == nsteps) break;
    }

    // normalize and store in place: lane holds O[q=col][d=dt*16+quad*4+r],
    // l_i is indexed by q=col -> direct reciprocal, aligned 8B stores.
    {
        const float inv = 1.0f / l_i;
        const size_t rowoff =
            (size_t)(b * S_LEN + q0 + col) * H_DIM + h * HEAD_DIM + quad * 4;
#pragma unroll
        for (int dt = 0; dt < 8; ++dt) {
            bf16x4 o;
#pragma unroll
            for (int r = 0; r < 4; ++r) o[r] = (bf16_t)(Oacc[dt][r] * inv);
            *(bf16x4*)(Q + rowoff + dt * 16) = o;
        }
    }
#undef ATTN_STEP
}

extern "C" void kernel_launch(void* const* d_in, const int* in_sizes, int n_in,
                              void* d_out, int out_size, void* d_ws, size_t ws_size,
                              hipStream_t stream) {
    const float* X    = (const float*)d_in[0];
    const float* cosb = (const float*)d_in[1];
    const float* sinb = (const float*)d_in[2];
    const float* Wq   = (const float*)d_in[3];
    const float* Wk   = (const float*)d_in[4];
    const float* Wv   = (const float*)d_in[5];
    const float* Wo   = (const float*)d_in[6];
    float* out = (float*)d_out;

    // ws (bf16): Xb 16MB | Wqkv 12MB (q 8, k 2, v 2 contiguous) | Wob 8MB |
    //            Q 16MB | K 4MB | V^T 4MB
    char* ws = (char*)d_ws;
    bf16_t* Xb    = (bf16_t*)(ws);
    bf16_t* Wqkvb = (bf16_t*)(ws + (16u << 20));
    bf16_t* Wkb   = (bf16_t*)(ws + (24u << 20));
    bf16_t* Wvb   = (bf16_t*)(ws + (26u << 20));
    bf16_t* Wob   = (bf16_t*)(ws + (28u << 20));
    bf16_t* qbuf  = (bf16_t*)(ws + (36u << 20));
    bf16_t* kbuf  = (bf16_t*)(ws + (52u << 20));
    bf16_t* vtbuf = (bf16_t*)(ws + (56u << 20));

    dim3 blk(256, 1, 1);
    const int ncvt = N_X + 2 * N_WQ + 2 * N_WK;   // /2048 = 9216 blocks
    cvt_all<<<dim3(ncvt / 2048, 1, 1), blk, 0, stream>>>(
        X, Wq, Wk, Wv, Wo, Xb, Wqkvb, Wkb, Wvb, Wob);

    gemm_qkv<<<dim3(NQKV / 128, NTOK / 128), blk, 0, stream>>>(
        Xb, Wqkvb, cosb, sinb, qbuf, kbuf, vtbuf);
    attn_fwd<<<dim3(512, 1, 1), dim3(512, 1, 1), 0, stream>>>(
        qbuf, kbuf, vtbuf, cosb, sinb);
    gemm_out<<<dim3(H_DIM / 128, NTOK / 128), blk, 0, stream>>>(qbuf, Wob, out);

    (void)in_sizes; (void)n_in; (void)out_size; (void)ws_size;
}

// Round 12
// 282.047 us; speedup vs baseline: 1.0787x; 1.0787x over previous
//
#include <hip/hip_runtime.h>
#include <hip/hip_bf16.h>
#include <stdint.h>

#define S_LEN 2048
#define H_DIM 2048
#define NHEADS 16
#define KVHEADS 4
#define HEAD_DIM 128
#define KV_DIM 512       // KVHEADS * HEAD_DIM
#define NTOK 4096        // B * S
#define NQKV 3072        // H_DIM + 2*KV_DIM

typedef __bf16 bf16_t;
typedef __bf16 bf16x8 __attribute__((ext_vector_type(8)));
typedef __bf16 bf16x4 __attribute__((ext_vector_type(4)));
typedef float f32x4 __attribute__((ext_vector_type(4)));

__device__ __forceinline__ f32x4 mfma16x16x32(bf16x8 a, bf16x8 b, f32x4 c) {
    return __builtin_amdgcn_mfma_f32_16x16x32_bf16(a, b, c, 0, 0, 0);
}

// async global->LDS, 16B per lane. LDS dest = wave-uniform base + lane*16;
// global address may be fully per-lane (scatter side is global).
__device__ __forceinline__ void gload_lds16(const bf16_t* g, bf16_t* l) {
    __builtin_amdgcn_global_load_lds(
        (__attribute__((address_space(1))) uint32_t*)(uintptr_t)g,
        (__attribute__((address_space(3))) uint32_t*)l, 16, 0, 0);
}

// Fused fp32->bf16 convert of all 5 tensors in one launch (8 elems/thread).
// NOTE (rounds 5/6/11): any weight permutation + RoPE-in-GEMM-epilogue
// variant regressed badly (occupancy + scattered loads). Keep this plain.
#define N_X  (NTOK * H_DIM)     // 8388608
#define N_WQ (H_DIM * H_DIM)    // 4194304
#define N_WK (KV_DIM * H_DIM)   // 1048576
__global__ __launch_bounds__(256) void cvt_all(const float* __restrict__ X,
                                               const float* __restrict__ Wq,
                                               const float* __restrict__ Wk,
                                               const float* __restrict__ Wv,
                                               const float* __restrict__ Wo,
                                               bf16_t* __restrict__ Xb,
                                               bf16_t* __restrict__ Wqb,
                                               bf16_t* __restrict__ Wkb,
                                               bf16_t* __restrict__ Wvb,
                                               bf16_t* __restrict__ Wob) {
    long i = (long)(blockIdx.x * 256 + threadIdx.x) * 8;
    const float* src;
    bf16_t* dst;
    if (i < N_X)                       { src = X;  dst = Xb; }
    else if ((i -= N_X) < N_WQ)        { src = Wq; dst = Wqb; }
    else if ((i -= N_WQ) < N_WK)       { src = Wk; dst = Wkb; }
    else if ((i -= N_WK) < N_WK)       { src = Wv; dst = Wvb; }
    else      { i -= N_WK;               src = Wo; dst = Wob; }
    const float4 a = *(const float4*)(src + i);
    const float4 b = *(const float4*)(src + i + 4);
    bf16x8 o;
    o[0] = (bf16_t)a.x; o[1] = (bf16_t)a.y; o[2] = (bf16_t)a.z; o[3] = (bf16_t)a.w;
    o[4] = (bf16_t)b.x; o[5] = (bf16_t)b.y; o[6] = (bf16_t)b.z; o[7] = (bf16_t)b.w;
    *(bf16x8*)(dst + i) = o;
}

// ---- GEMM main loop, BK=32 variant (m97 structure) ----
// Used by gemm_qkv (768 blocks, ~3/CU): at this concurrency the barrier
// drains are hidden by inter-block wave overlap (r7-r10 A/B: BK=32
// two-barrier 69us beats BK=64 76.5us and dbuf 80.4us on this grid).
#define GEMM_BODY32(A_, W_, K_)                                                \
    __shared__ alignas(16) bf16_t As[128 * 32];                                \
    __shared__ alignas(16) bf16_t Bs[128 * 32];                                \
    const int tid  = threadIdx.x;                                              \
    const int wave = tid >> 6;                                                 \
    const int lane = tid & 63;                                                 \
    const int col  = lane & 15;                                                \
    const int quad = lane >> 4;                                                \
    const int m0 = blockIdx.y * 128;                                           \
    const int n0 = blockIdx.x * 128;                                           \
    const int wm = (wave >> 1) * 64;                                           \
    const int wn = (wave & 1) * 64;                                            \
    const int r0 = tid >> 2;                                                   \
    const int kk = (tid & 3) * 8;                                              \
    const bf16_t* a0 = (A_) + (size_t)(m0 + r0) * (K_) + kk;                   \
    const bf16_t* a1 = a0 + (size_t)64 * (K_);                                 \
    const bf16_t* b0 = (W_) + (size_t)(n0 + r0) * (K_) + kk;                   \
    const bf16_t* b1 = b0 + (size_t)64 * (K_);                                 \
    bf16_t* lA0 = As + tid * 8;                                                \
    bf16_t* lA1 = As + 2048 + tid * 8;                                         \
    bf16_t* lB0 = Bs + tid * 8;                                                \
    bf16_t* lB1 = Bs + 2048 + tid * 8;                                         \
    f32x4 acc[4][4];                                                           \
    _Pragma("unroll") for (int mi = 0; mi < 4; ++mi)                           \
        _Pragma("unroll") for (int ni = 0; ni < 4; ++ni)                       \
            acc[mi][ni] = (f32x4){0.f, 0.f, 0.f, 0.f};                         \
    for (int k0 = 0; k0 < (K_); k0 += 32) {                                    \
        __syncthreads();                                                       \
        gload_lds16(a0 + k0, lA0);                                             \
        gload_lds16(a1 + k0, lA1);                                             \
        gload_lds16(b0 + k0, lB0);                                             \
        gload_lds16(b1 + k0, lB1);                                             \
        __syncthreads();                                                       \
        bf16x8 av[4], bv[4];                                                   \
        _Pragma("unroll") for (int i = 0; i < 4; ++i) {                        \
            av[i] = *(const bf16x8*)(As + (wm + i * 16 + col) * 32 + quad * 8);\
            bv[i] = *(const bf16x8*)(Bs + (wn + i * 16 + col) * 32 + quad * 8);\
        }                                                                      \
        _Pragma("unroll") for (int mi = 0; mi < 4; ++mi)                       \
            _Pragma("unroll") for (int ni = 0; ni < 4; ++ni)                   \
                acc[mi][ni] = mfma16x16x32(av[mi], bv[ni], acc[mi][ni]);       \
    }

// ---- GEMM main loop, BK=64 variant with XOR-swizzled staging ----
// Used by gemm_out (128 blocks, ~0.5/CU): no neighbor waves to hide the
// per-step vmcnt drain, so halving the barrier count pays (round-7/8 A/B:
// ~ -15 us on this grid). Reads are conflict-free via both-sides swizzle.
#define GEMM_BODY64(A_, W_, K_)                                                \
    __shared__ alignas(16) bf16_t As[128 * 64];                                \
    __shared__ alignas(16) bf16_t Bs[128 * 64];                                \
    const int tid  = threadIdx.x;                                              \
    const int wave = tid >> 6;                                                 \
    const int lane = tid & 63;                                                 \
    const int col  = lane & 15;                                                \
    const int quad = lane >> 4;                                                \
    const int m0 = blockIdx.y * 128;                                           \
    const int n0 = blockIdx.x * 128;                                           \
    const int wm = (wave >> 1) * 64;                                           \
    const int wn = (wave & 1) * 64;                                            \
    const int r0 = tid >> 3;             /* staging row in 32-row chunk */     \
    const int kk = ((tid & 7) ^ (r0 & 7)) * 8;  /* pre-swizzled k-chunk */     \
    const bf16_t* ab = (A_) + (size_t)(m0 + r0) * (K_) + kk;                   \
    const bf16_t* bb = (W_) + (size_t)(n0 + r0) * (K_) + kk;                   \
    bf16_t* lA = As + tid * 8;                                                 \
    bf16_t* lB = Bs + tid * 8;                                                 \
    const int swz = col & 7;                                                   \
    f32x4 acc[4][4];                                                           \
    _Pragma("unroll") for (int mi = 0; mi < 4; ++mi)                           \
        _Pragma("unroll") for (int ni = 0; ni < 4; ++ni)                       \
            acc[mi][ni] = (f32x4){0.f, 0.f, 0.f, 0.f};                         \
    for (int k0 = 0; k0 < (K_); k0 += 64) {                                    \
        __syncthreads();                                                       \
        _Pragma("unroll") for (int c = 0; c < 4; ++c) {                        \
            gload_lds16(ab + k0 + (size_t)(c * 32) * (K_), lA + c * 2048);     \
            gload_lds16(bb + k0 + (size_t)(c * 32) * (K_), lB + c * 2048);     \
        }                                                                      \
        __syncthreads();                                                       \
        _Pragma("unroll") for (int h = 0; h < 2; ++h) {                        \
            bf16x8 av[4], bv[4];                                               \
            _Pragma("unroll") for (int i = 0; i < 4; ++i) {                    \
                av[i] = *(const bf16x8*)(As + (wm + i * 16 + col) * 64 +       \
                                         (((h * 4 + quad) ^ swz) << 3));       \
                bv[i] = *(const bf16x8*)(Bs + (wn + i * 16 + col) * 64 +       \
                                         (((h * 4 + quad) ^ swz) << 3));       \
            }                                                                  \
            _Pragma("unroll") for (int mi = 0; mi < 4; ++mi)                   \
                _Pragma("unroll") for (int ni = 0; ni < 4; ++ni)               \
                    acc[mi][ni] = mfma16x16x32(av[mi], bv[ni], acc[mi][ni]);   \
        }                                                                      \
    }

// Fused QKV projection: C row-major views into qbuf [M][2048] (n<2048),
// kbuf [M][512] (2048<=n<2560), and V^T layout [b][kvh*128+d][s] (n>=2560).
__global__ __launch_bounds__(256) void gemm_qkv(const bf16_t* __restrict__ A,
                                                const bf16_t* __restrict__ W,
                                                bf16_t* __restrict__ qbuf,
                                                bf16_t* __restrict__ kbuf,
                                                bf16_t* __restrict__ vtbuf) {
    GEMM_BODY32(A, W, H_DIM)
    const int ng = n0 + wn;   // 64-aligned; q/k/v boundaries are 64-aligned
    if (ng < H_DIM) {
#pragma unroll
        for (int mi = 0; mi < 4; ++mi)
#pragma unroll
            for (int ni = 0; ni < 4; ++ni)
#pragma unroll
                for (int r = 0; r < 4; ++r)
                    qbuf[(size_t)(m0 + wm + mi * 16 + quad * 4 + r) * H_DIM +
                         ng + ni * 16 + col] = (bf16_t)acc[mi][ni][r];
    } else if (ng < H_DIM + KV_DIM) {
#pragma unroll
        for (int mi = 0; mi < 4; ++mi)
#pragma unroll
            for (int ni = 0; ni < 4; ++ni)
#pragma unroll
                for (int r = 0; r < 4; ++r)
                    kbuf[(size_t)(m0 + wm + mi * 16 + quad * 4 + r) * KV_DIM +
                         ng - H_DIM + ni * 16 + col] = (bf16_t)acc[mi][ni][r];
    } else {
#pragma unroll
        for (int mi = 0; mi < 4; ++mi) {
            const int m = m0 + wm + mi * 16 + quad * 4;
#pragma unroll
            for (int ni = 0; ni < 4; ++ni) {
                const int nv = ng - (H_DIM + KV_DIM) + ni * 16 + col;
                const size_t off =
                    ((size_t)(m >> 11) * KV_DIM + nv) * S_LEN + (m & (S_LEN - 1));
                bf16x4 o;
#pragma unroll
                for (int r = 0; r < 4; ++r) o[r] = (bf16_t)acc[mi][ni][r];
                *(bf16x4*)(vtbuf + off) = o;
            }
        }
    }
}

// O projection: fp32 output.
__global__ __launch_bounds__(256) void gemm_out(const bf16_t* __restrict__ A,
                                                const bf16_t* __restrict__ W,
                                                float* __restrict__ C) {
    GEMM_BODY64(A, W, H_DIM)
#pragma unroll
    for (int mi = 0; mi < 4; ++mi)
#pragma unroll
        for (int ni = 0; ni < 4; ++ni)
#pragma unroll
            for (int r = 0; r < 4; ++r)
                C[(size_t)(m0 + wm + mi * 16 + quad * 4 + r) * H_DIM +
                  n0 + wn + ni * 16 + col] = (float)acc[mi][ni][r];
}

#define QSCALE_LOG2E 0.12753102813264324f  // (1/sqrt(128)) * log2(e)

// In-place RoPE on K ONLY [NTOK][512] (4 kv heads) — Q-RoPE is fused into
// the attn prologue (verified round 11). Vectorized: 8 rotation pairs per
// thread (bf16x8 loads/stores, float4 cos/sin). 1/5 the work of the old
// 20-head rope kernel.
__global__ __launch_bounds__(256) void rope_k(bf16_t* __restrict__ Kb,
                                              const float* __restrict__ cosb,
                                              const float* __restrict__ sinb) {
    const int idx  = blockIdx.x * 256 + threadIdx.x;  // NTOK*4*8 threads
    const int d8   = (idx & 7) * 8;
    const int rem  = idx >> 3;
    const int head = rem & 3;
    const int row  = rem >> 2;
    const int s = row & (S_LEN - 1);
    const float4* cb = (const float4*)(cosb + s * HEAD_DIM);
    const float4* sb = (const float4*)(sinb + s * HEAD_DIM);
    float c0[8], s0[8], c1[8], s1[8];
    *(float4*)&c0[0] = cb[d8 >> 2];        *(float4*)&c0[4] = cb[(d8 >> 2) + 1];
    *(float4*)&s0[0] = sb[d8 >> 2];        *(float4*)&s0[4] = sb[(d8 >> 2) + 1];
    *(float4*)&c1[0] = cb[16 + (d8 >> 2)]; *(float4*)&c1[4] = cb[17 + (d8 >> 2)];
    *(float4*)&s1[0] = sb[16 + (d8 >> 2)]; *(float4*)&s1[4] = sb[17 + (d8 >> 2)];
    bf16_t* base = Kb + (size_t)row * KV_DIM + head * HEAD_DIM;
    const bf16x8 lo = *(const bf16x8*)(base + d8);
    const bf16x8 hi = *(const bf16x8*)(base + d8 + 64);
    bf16x8 olo, ohi;
#pragma unroll
    for (int u = 0; u < 8; ++u) {
        const float lf = (float)lo[u];
        const float hf = (float)hi[u];
        olo[u] = (bf16_t)(lf * c0[u] - hf * s0[u]);
        ohi[u] = (bf16_t)(hf * c1[u] + lf * s1[u]);
    }
    *(bf16x8*)(base + d8)      = olo;
    *(bf16x8*)(base + d8 + 64) = ohi;
}

#define NEG_BIG (-1e30f)
#define TJ 64          // kv tile width
#define DEFER_THR 8.0f // defer-max threshold, log2 units (P bounded by 2^8)

// Flash attention, causal, transposed-score form.
// 8-wave (512-thread) blocks; waves 0-3 own q-tile 2i, waves 4-7 own 2i+1;
// shared K/V staging stream; complementary CU pairing (i = b? 63-jp : jp).
// Q-RoPE is FUSED into the prologue (verified round 11): qf[t][u] holds dim
// d = t*32+quad*8+u, its RoPE partner d+64 is qf[t+2][u] -- same lane, so
// the rotation (+ the scale*log2e fold) is 64 FMAs + 16 L2-hit float4
// loads, once per block, hidden under stage(0,0)'s DMA. Q in memory is the
// RAW projection.
// PV is K=32 MFMA with P^T staged through wave-private LDS scratch Ps;
// one __syncthreads per kv-step; PV operand order mfma(vf, aP) gives O^T
// (O[q=col][d]) -> broadcast-free alpha/l rescale and aligned bf16x4 stores.
__global__ __launch_bounds__(512, 4) void attn_fwd(bf16_t* __restrict__ Q,
                                                   const bf16_t* __restrict__ Kb,
                                                   const bf16_t* __restrict__ Vt,
                                                   const float* __restrict__ cosb,
                                                   const float* __restrict__ sinb) {
    const int id   = blockIdx.x;       // 0..511
    const int jp   = id & 63;
    const int kvh  = (id >> 6) & 3;
    const int b    = id >> 8;
    const int i    = b ? (63 - jp) : jp;   // complementary pairing per CU
    const int tid  = threadIdx.x;
    const int wave = tid >> 6;
    const int lane = tid & 63;
    const int col  = lane & 15;
    const int quad = lane >> 4;
    const int grp  = wave >> 2;        // 0: tile 2i, 1: tile 2i+1
    const int h    = kvh * 4 + (wave & 3);
    const int q0   = (2 * i + grp) * 16;
    const int nsteps = (i >> 1) + 1;
    const int swz  = col & 7;          // read-side swizzle key

    __shared__ alignas(16) bf16_t Ks[2][TJ * HEAD_DIM];    // 16 KB each
    __shared__ alignas(16) bf16_t Vs[2][HEAD_DIM * TJ];    // 16 KB each
    __shared__ alignas(16) bf16_t Ps[8 * 1024];            // 16 KB, wave-priv

    const bf16_t* kbase = Kb + (size_t)(b * S_LEN) * KV_DIM + kvh * HEAD_DIM;
    const bf16_t* vtb   = Vt + (size_t)(b * KVHEADS + kvh) * HEAD_DIM * S_LEN;

    // per-lane global element offsets for the 2 K + 2 V staging DMAs
    int kgoff[2], vgoff[2];
#pragma unroll
    for (int im = 0; im < 2; ++im) {
        const int s = im * 512 + tid;
        const int jr = s >> 4, c = (s & 15) ^ (jr & 7);
        kgoff[im] = jr * KV_DIM + c * 8;
        const int d = s >> 3, cj = (s & 7) ^ (d & 7);
        vgoff[im] = d * S_LEN + cj * 8;
    }
    auto stage = [&](int buf, int j0) {
        const bf16_t* kb = kbase + (size_t)j0 * KV_DIM;
        const bf16_t* vb = vtb + j0;
#pragma unroll
        for (int im = 0; im < 2; ++im) {
            gload_lds16(kb + kgoff[im], &Ks[buf][(im * 512 + wave * 64) * 8]);
            gload_lds16(vb + vgoff[im], &Vs[buf][(im * 512 + wave * 64) * 8]);
        }
    };

    // hoisted fragment LDS byte addrs; tile index goes into imm offsets:
    // K frag (t,jc): kaddr[t] + jc*4096;  V frag (half,dt): vb0/1 + dt*2048
    int kaddr[4];
#pragma unroll
    for (int t = 0; t < 4; ++t)
        kaddr[t] = col * 256 + (((4 * t + quad) ^ swz) << 4);
    const int vb0 = col * 128 + ((quad ^ swz) << 4);
    const int vb1 = col * 128 + (((quad + 4) ^ swz) << 4);
    // P^T scratch offsets (wave-private 2 KB slice of Ps)
    int pwoff[4];
#pragma unroll
    for (int jc = 0; jc < 4; ++jc)
        pwoff[jc] = wave * 2048 +
                    ((col * 128 + jc * 32 + quad * 8) ^ (swz << 4));
    const int ap0 = wave * 2048 + ((col * 128 + quad * 16) ^ (swz << 4));
    const int ap1 = wave * 2048 + ((col * 128 + 64 + quad * 16) ^ (swz << 4));

#define ATTN_STEP(JT, BUF)                                                     \
    {                                                                          \
        const int jt_ = (JT);                                                  \
        const bool last_ = (jt_ == nsteps - 1);                                \
        __syncthreads();  /* vmcnt(0) drain: buf BUF staged; prev reads done */\
        if (!last_) stage((BUF) ^ 1, (jt_ + 1) * TJ);                          \
        const char* ksb = (const char*)Ks[(BUF)];                              \
        const char* vsb = (const char*)Vs[(BUF)];                              \
        char* pwb = (char*)Ps;          /* wave-private P^T scratch */         \
        f32x4 sc[4];                                                           \
        _Pragma("unroll") for (int jc = 0; jc < 4; ++jc)                       \
            sc[jc] = (f32x4){0.f, 0.f, 0.f, 0.f};                              \
        __builtin_amdgcn_s_setprio(1);                                         \
        _Pragma("unroll") for (int t = 0; t < 4; ++t)                          \
            _Pragma("unroll") for (int jc = 0; jc < 4; ++jc)                   \
                sc[jc] = mfma16x16x32(                                         \
                    *(const bf16x8*)(ksb + kaddr[t] + jc * 4096), qf[t],       \
                    sc[jc]);                                                   \
        __builtin_amdgcn_s_setprio(0);                                         \
        if (last_) {                                                           \
            const int j0_ = jt_ * TJ;                                          \
            const int q_ = q0 + col;                                           \
            _Pragma("unroll") for (int jc = 0; jc < 4; ++jc)                   \
                _Pragma("unroll") for (int r = 0; r < 4; ++r) {                \
                    const int j = j0_ + jc * 16 + quad * 4 + r;                \
                    if (j > q_) sc[jc][r] = NEG_BIG;                           \
                }                                                              \
        }                                                                      \
        float mx = sc[0][0];                                                   \
        _Pragma("unroll") for (int jc = 0; jc < 4; ++jc)                       \
            _Pragma("unroll") for (int r = 0; r < 4; ++r)                      \
                mx = fmaxf(mx, sc[jc][r]);                                     \
        /* per-lane partial max is a lower bound of the column max: if no  */  \
        /* lane exceeds m_i+THR, no column max does -> skip reduce+rescale */  \
        if (!__all(mx <= m_i + DEFER_THR)) {                                   \
            mx = fmaxf(mx, __shfl_xor(mx, 16));                                \
            mx = fmaxf(mx, __shfl_xor(mx, 32));                                \
            const float mn = fmaxf(m_i, mx);                                   \
            const float alpha = __builtin_amdgcn_exp2f(m_i - mn);              \
            m_i = mn;                                                          \
            l_i *= alpha;                                                      \
            _Pragma("unroll") for (int dt = 0; dt < 8; ++dt)                   \
                Oacc[dt] *= alpha;  /* O rows are q=col: no broadcast */       \
        }                                                                      \
        float sum = 0.f;                                                       \
        bf16x4 pb[4];                                                          \
        _Pragma("unroll") for (int jc = 0; jc < 4; ++jc)                       \
            _Pragma("unroll") for (int r = 0; r < 4; ++r) {                    \
                const float pe = __builtin_amdgcn_exp2f(sc[jc][r] - m_i);      \
                sum += pe;                                                     \
                pb[jc][r] = (bf16_t)pe;                                        \
            }                                                                  \
        _Pragma("unroll") for (int jc = 0; jc < 4; ++jc)                       \
            *(bf16x4*)(pwb + pwoff[jc]) = pb[jc];                              \
        sum += __shfl_xor(sum, 16);                                            \
        sum += __shfl_xor(sum, 32);                                            \
        l_i += sum;                                                            \
        asm volatile("s_waitcnt lgkmcnt(0)" ::: "memory");  /* P visible */    \
        const bf16x8 aP0 = *(const bf16x8*)(pwb + ap0);                        \
        const bf16x8 aP1 = *(const bf16x8*)(pwb + ap1);                        \
        __builtin_amdgcn_s_setprio(1);                                         \
        _Pragma("unroll") for (int dt = 0; dt < 8; ++dt) {                     \
            const bf16x8 vf0 = *(const bf16x8*)(vsb + vb0 + dt * 2048);        \
            const bf16x8 vf1 = *(const bf16x8*)(vsb + vb1 + dt * 2048);        \
            Oacc[dt] = mfma16x16x32(vf1, aP1,                                  \
                       mfma16x16x32(vf0, aP0, Oacc[dt]));                      \
        }                                                                      \
        __builtin_amdgcn_s_setprio(0);                                         \
    }

    stage(0, 0);

    // Q load + in-register RoPE (+ scale*log2e fold). qf[t][u] holds dim
    // d = t*32 + quad*8 + u; partner d+64 lives in qf[t+2][u].
    bf16x8 qf[4];
    {
        const bf16_t* qp = Q + (size_t)(b * S_LEN + q0 + col) * H_DIM +
                           h * HEAD_DIM + quad * 8;
#pragma unroll
        for (int t = 0; t < 4; ++t) qf[t] = *(const bf16x8*)(qp + t * 32);
        const float* cq = cosb + (size_t)(q0 + col) * HEAD_DIM + quad * 8;
        const float* sq = sinb + (size_t)(q0 + col) * HEAD_DIM + quad * 8;
#pragma unroll
        for (int t = 0; t < 2; ++t) {
            float c0[8], s0[8], c1[8], s1[8];
            *(float4*)&c0[0] = *(const float4*)(cq + t * 32);
            *(float4*)&c0[4] = *(const float4*)(cq + t * 32 + 4);
            *(float4*)&s0[0] = *(const float4*)(sq + t * 32);
            *(float4*)&s0[4] = *(const float4*)(sq + t * 32 + 4);
            *(float4*)&c1[0] = *(const float4*)(cq + t * 32 + 64);
            *(float4*)&c1[4] = *(const float4*)(cq + t * 32 + 68);
            *(float4*)&s1[0] = *(const float4*)(sq + t * 32 + 64);
            *(float4*)&s1[4] = *(const float4*)(sq + t * 32 + 68);
#pragma unroll
            for (int u = 0; u < 8; ++u) {
                const float lo = (float)qf[t][u];
                const float hi = (float)qf[t + 2][u];
                qf[t][u] =
                    (bf16_t)((lo * c0[u] - hi * s0[u]) * QSCALE_LOG2E);
                qf[t + 2][u] =
                    (bf16_t)((hi * c1[u] + lo * s1[u]) * QSCALE_LOG2E);
            }
        }
    }
    f32x4 Oacc[8];
#pragma unroll
    for (int dt = 0; dt < 8; ++dt) Oacc[dt] = (f32x4){0.f, 0.f, 0.f, 0.f};
    float m_i = NEG_BIG, l_i = 0.f;

    int jt = 0;
    while (true) {
        ATTN_STEP(jt, 0)
        if (++jt == nsteps) break;
        ATTN_STEP(jt, 1)
        if (++jt == nsteps) break;
    }

    // normalize and store in place: lane holds O[q=col][d=dt*16+quad*4+r],
    // l_i is indexed by q=col -> direct reciprocal, aligned 8B stores.
    {
        const float inv = 1.0f / l_i;
        const size_t rowoff =
            (size_t)(b * S_LEN + q0 + col) * H_DIM + h * HEAD_DIM + quad * 4;
#pragma unroll
        for (int dt = 0; dt < 8; ++dt) {
            bf16x4 o;
#pragma unroll
            for (int r = 0; r < 4; ++r) o[r] = (bf16_t)(Oacc[dt][r] * inv);
            *(bf16x4*)(Q + rowoff + dt * 16) = o;
        }
    }
#undef ATTN_STEP
}

extern "C" void kernel_launch(void* const* d_in, const int* in_sizes, int n_in,
                              void* d_out, int out_size, void* d_ws, size_t ws_size,
                              hipStream_t stream) {
    const float* X    = (const float*)d_in[0];
    const float* cosb = (const float*)d_in[1];
    const float* sinb = (const float*)d_in[2];
    const float* Wq   = (const float*)d_in[3];
    const float* Wk   = (const float*)d_in[4];
    const float* Wv   = (const float*)d_in[5];
    const float* Wo   = (const float*)d_in[6];
    float* out = (float*)d_out;

    // ws (bf16): Xb 16MB | Wqkv 12MB (q 8, k 2, v 2 contiguous) | Wob 8MB |
    //            Q 16MB | K 4MB | V^T 4MB
    char* ws = (char*)d_ws;
    bf16_t* Xb    = (bf16_t*)(ws);
    bf16_t* Wqkvb = (bf16_t*)(ws + (16u << 20));
    bf16_t* Wkb   = (bf16_t*)(ws + (24u << 20));
    bf16_t* Wvb   = (bf16_t*)(ws + (26u << 20));
    bf16_t* Wob   = (bf16_t*)(ws + (28u << 20));
    bf16_t* qbuf  = (bf16_t*)(ws + (36u << 20));
    bf16_t* kbuf  = (bf16_t*)(ws + (52u << 20));
    bf16_t* vtbuf = (bf16_t*)(ws + (56u << 20));

    dim3 blk(256, 1, 1);
    const int ncvt = N_X + 2 * N_WQ + 2 * N_WK;   // /2048 = 9216 blocks
    cvt_all<<<dim3(ncvt / 2048, 1, 1), blk, 0, stream>>>(
        X, Wq, Wk, Wv, Wo, Xb, Wqkvb, Wkb, Wvb, Wob);

    gemm_qkv<<<dim3(NQKV / 128, NTOK / 128), blk, 0, stream>>>(
        Xb, Wqkvb, qbuf, kbuf, vtbuf);
    rope_k<<<dim3((NTOK * 4 * 8) / 256), blk, 0, stream>>>(kbuf, cosb, sinb);
    attn_fwd<<<dim3(512, 1, 1), dim3(512, 1, 1), 0, stream>>>(
        qbuf, kbuf, vtbuf, cosb, sinb);
    gemm_out<<<dim3(H_DIM / 128, NTOK / 128), blk, 0, stream>>>(qbuf, Wob, out);

    (void)in_sizes; (void)n_in; (void)out_size; (void)ws_size;
}